// Round 1
// baseline (92.417 us; speedup 1.0000x reference)
//
#include <hip/hip_runtime.h>
#include <hip/hip_bf16.h>
#include <float.h>

#define NGROUPS 128
#define CAP 1024  // LDS staging capacity per group (points); groups are ~128±12

// ws layout (ints): [0,128) counts | [128,256) offsets | [256,384) cursor | [384,384+M) order

__global__ void kde_zero(int* __restrict__ counts) {
    int t = threadIdx.x;
    if (t < NGROUPS) counts[t] = 0;
}

__global__ void kde_count(const int* __restrict__ idx, int M, int* __restrict__ counts) {
    int i = blockIdx.x * blockDim.x + threadIdx.x;
    if (i < M) atomicAdd(&counts[idx[i]], 1);
}

__global__ void kde_scan(const int* __restrict__ counts,
                         int* __restrict__ offsets,
                         int* __restrict__ cursor) {
    if (threadIdx.x == 0 && blockIdx.x == 0) {
        int acc = 0;
        for (int g = 0; g < NGROUPS; ++g) {
            offsets[g] = acc;
            cursor[g]  = acc;
            acc += counts[g];
        }
    }
}

__global__ void kde_scatter(const int* __restrict__ idx, int M,
                            int* __restrict__ cursor, int* __restrict__ order) {
    int i = blockIdx.x * blockDim.x + threadIdx.x;
    if (i < M) {
        int g = idx[i];
        int pos = atomicAdd(&cursor[g], 1);
        order[pos] = i;
    }
}

// One block per group. Stage group coords in LDS; each thread owns member(s),
// scans all c candidates, keeps 16 smallest squared distances in a sorted
// 16-register chain (all static indexing -> stays in VGPRs).
__global__ __launch_bounds__(256) void kde_select(
        const float* __restrict__ x,
        const int* __restrict__ order,
        const int* __restrict__ counts,
        const int* __restrict__ offsets,
        const int* __restrict__ Kptr,
        float* __restrict__ out) {
    __shared__ float sx[CAP], sy[CAP], sz[CAP];

    const int g   = blockIdx.x;
    const int c   = counts[g];
    const int off = offsets[g];
    const int K   = Kptr[0];

    const int staged = (c < CAP) ? c : CAP;
    for (int t = threadIdx.x; t < staged; t += blockDim.x) {
        int j = order[off + t];
        sx[t] = x[3 * j + 0];
        sy[t] = x[3 * j + 1];
        sz[t] = x[3 * j + 2];
    }
    __syncthreads();

    for (int mi = threadIdx.x; mi < c; mi += blockDim.x) {
        const int m = order[off + mi];
        float xm, ym, zm;
        if (mi < staged) { xm = sx[mi]; ym = sy[mi]; zm = sz[mi]; }
        else { xm = x[3 * m + 0]; ym = x[3 * m + 1]; zm = x[3 * m + 2]; }

        float s0 = FLT_MAX, s1 = FLT_MAX, s2 = FLT_MAX, s3 = FLT_MAX;
        float s4 = FLT_MAX, s5 = FLT_MAX, s6 = FLT_MAX, s7 = FLT_MAX;
        float s8 = FLT_MAX, s9 = FLT_MAX, s10 = FLT_MAX, s11 = FLT_MAX;
        float s12 = FLT_MAX, s13 = FLT_MAX, s14 = FLT_MAX, s15 = FLT_MAX;

#define KNN_INSERT(dval)                                                      \
        do {                                                                  \
            float v_ = (dval);                                                \
            if (v_ < s15) {                                                   \
                float tt_;                                                    \
                if (v_ < s0)  { tt_ = s0;  s0  = v_; v_ = tt_; }              \
                if (v_ < s1)  { tt_ = s1;  s1  = v_; v_ = tt_; }              \
                if (v_ < s2)  { tt_ = s2;  s2  = v_; v_ = tt_; }              \
                if (v_ < s3)  { tt_ = s3;  s3  = v_; v_ = tt_; }              \
                if (v_ < s4)  { tt_ = s4;  s4  = v_; v_ = tt_; }              \
                if (v_ < s5)  { tt_ = s5;  s5  = v_; v_ = tt_; }              \
                if (v_ < s6)  { tt_ = s6;  s6  = v_; v_ = tt_; }              \
                if (v_ < s7)  { tt_ = s7;  s7  = v_; v_ = tt_; }              \
                if (v_ < s8)  { tt_ = s8;  s8  = v_; v_ = tt_; }              \
                if (v_ < s9)  { tt_ = s9;  s9  = v_; v_ = tt_; }              \
                if (v_ < s10) { tt_ = s10; s10 = v_; v_ = tt_; }              \
                if (v_ < s11) { tt_ = s11; s11 = v_; v_ = tt_; }              \
                if (v_ < s12) { tt_ = s12; s12 = v_; v_ = tt_; }              \
                if (v_ < s13) { tt_ = s13; s13 = v_; v_ = tt_; }              \
                if (v_ < s14) { tt_ = s14; s14 = v_; v_ = tt_; }              \
                s15 = v_;                                                     \
            }                                                                 \
        } while (0)

        // LDS-staged candidates (covers everything in practice)
        for (int j = 0; j < staged; ++j) {
            float dx = sx[j] - xm;
            float dy = sy[j] - ym;
            float dz = sz[j] - zm;
            float d2 = dx * dx + dy * dy + dz * dz;
            KNN_INSERT(d2);
        }
        // overflow candidates (c > CAP) — read via L2; essentially never runs
        for (int j = staged; j < c; ++j) {
            int o = order[off + j];
            float dx = x[3 * o + 0] - xm;
            float dy = x[3 * o + 1] - ym;
            float dz = x[3 * o + 2] - zm;
            float d2 = dx * dx + dy * dy + dz * dz;
            KNN_INSERT(d2);
        }
#undef KNN_INSERT

        // s15 = K-th smallest squared distance (includes self 0).
        // dim = NI-1 = 2: volume = pi * r^2 = pi * s15 (no sqrt needed).
        float p;
        if (c < K) {
            p = 1.0f / (float)c;
        } else {
            p = 3.14159265358979323846f * s15 / (float)(K - 1);
        }
        out[m] = p;
    }
}

extern "C" void kernel_launch(void* const* d_in, const int* in_sizes, int n_in,
                              void* d_out, int out_size, void* d_ws, size_t ws_size,
                              hipStream_t stream) {
    const float* x   = (const float*)d_in[0];
    const int*   idx = (const int*)d_in[1];
    const int*   Kp  = (const int*)d_in[2];
    float* out = (float*)d_out;

    const int M = in_sizes[1];  // 16384

    int* ws      = (int*)d_ws;
    int* counts  = ws;
    int* offsets = ws + NGROUPS;
    int* cursor  = ws + 2 * NGROUPS;
    int* order   = ws + 3 * NGROUPS;

    const int threads = 256;
    const int blocksM = (M + threads - 1) / threads;

    kde_zero<<<1, NGROUPS, 0, stream>>>(counts);
    kde_count<<<blocksM, threads, 0, stream>>>(idx, M, counts);
    kde_scan<<<1, 64, 0, stream>>>(counts, offsets, cursor);
    kde_scatter<<<blocksM, threads, 0, stream>>>(idx, M, cursor, order);
    kde_select<<<NGROUPS, threads, 0, stream>>>(x, order, counts, offsets, Kp, out);
}

// Round 2
// 38.649 us; speedup vs baseline: 2.3912x; 2.3912x over previous
//
#include <hip/hip_runtime.h>
#include <hip/hip_bf16.h>
#include <float.h>

#define NGROUPS 128

// ws layout (ints): [0,128) counts | [128,256) offsets | [256,256+M) order

// ---------------- bucket: count + scan + scatter in ONE block ----------------
__global__ __launch_bounds__(1024) void kde_bucket(const int* __restrict__ idx, int M,
                                                   int* __restrict__ counts,
                                                   int* __restrict__ offsets,
                                                   int* __restrict__ order) {
    __shared__ int lc[NGROUPS];
    __shared__ int lo[NGROUPS];
    const int t = threadIdx.x;
    if (t < NGROUPS) lc[t] = 0;
    __syncthreads();
    for (int i = t; i < M; i += 1024) atomicAdd(&lc[idx[i]], 1);
    __syncthreads();
    if (t == 0) {
        int acc = 0;
        for (int g = 0; g < NGROUPS; ++g) { lo[g] = acc; acc += lc[g]; }
    }
    __syncthreads();
    if (t < NGROUPS) { counts[t] = lc[t]; offsets[t] = lo[t]; }
    __syncthreads();
    if (t < NGROUPS) lc[t] = lo[t];   // reuse lc as scatter cursor
    __syncthreads();
    for (int i = t; i < M; i += 1024) {
        int g = idx[i];
        int p = atomicAdd(&lc[g], 1);
        order[p] = i;
    }
}

// ---------------- select: one 64-lane wave per point ----------------
// Per lane: sorted ascending top-16 of its strided candidate slice (static
// register chain). Then K cooperative pops: wave-min of heads via DPP
// (VALU pipe), ballot -> leader pops its head. Exact for any c: one lane can
// contribute at most K<=16 values to the global top-K.

#define DPP_MIN_STEP(v, CTRL)                                                  \
    v = fminf(v, __int_as_float(__builtin_amdgcn_update_dpp(                   \
            0x7f7fffff /*FLT_MAX bits*/, __float_as_int(v), CTRL, 0xf, 0xf,    \
            false)))

__global__ __launch_bounds__(256) void kde_select(
        const float* __restrict__ x,
        const int* __restrict__ idx,
        const int* __restrict__ order,
        const int* __restrict__ counts,
        const int* __restrict__ offsets,
        const int* __restrict__ Kptr,
        int M,
        float* __restrict__ out) {
    const int wid  = (blockIdx.x << 2) | (threadIdx.x >> 6);  // point id
    const int lane = threadIdx.x & 63;
    if (wid >= M) return;

    const int g   = idx[wid];
    const int c   = counts[g];
    const int off = offsets[g];
    const int K   = Kptr[0];

    const float xm = x[3 * wid + 0];
    const float ym = x[3 * wid + 1];
    const float zm = x[3 * wid + 2];

    float s0 = FLT_MAX, s1 = FLT_MAX, s2 = FLT_MAX, s3 = FLT_MAX;
    float s4 = FLT_MAX, s5 = FLT_MAX, s6 = FLT_MAX, s7 = FLT_MAX;
    float s8 = FLT_MAX, s9 = FLT_MAX, s10 = FLT_MAX, s11 = FLT_MAX;
    float s12 = FLT_MAX, s13 = FLT_MAX, s14 = FLT_MAX, s15 = FLT_MAX;

#define KNN_INSERT(dval)                                                      \
    do {                                                                      \
        float v_ = (dval);                                                    \
        if (v_ < s15) {                                                       \
            float tt_;                                                        \
            if (v_ < s0)  { tt_ = s0;  s0  = v_; v_ = tt_; }                  \
            if (v_ < s1)  { tt_ = s1;  s1  = v_; v_ = tt_; }                  \
            if (v_ < s2)  { tt_ = s2;  s2  = v_; v_ = tt_; }                  \
            if (v_ < s3)  { tt_ = s3;  s3  = v_; v_ = tt_; }                  \
            if (v_ < s4)  { tt_ = s4;  s4  = v_; v_ = tt_; }                  \
            if (v_ < s5)  { tt_ = s5;  s5  = v_; v_ = tt_; }                  \
            if (v_ < s6)  { tt_ = s6;  s6  = v_; v_ = tt_; }                  \
            if (v_ < s7)  { tt_ = s7;  s7  = v_; v_ = tt_; }                  \
            if (v_ < s8)  { tt_ = s8;  s8  = v_; v_ = tt_; }                  \
            if (v_ < s9)  { tt_ = s9;  s9  = v_; v_ = tt_; }                  \
            if (v_ < s10) { tt_ = s10; s10 = v_; v_ = tt_; }                  \
            if (v_ < s11) { tt_ = s11; s11 = v_; v_ = tt_; }                  \
            if (v_ < s12) { tt_ = s12; s12 = v_; v_ = tt_; }                  \
            if (v_ < s13) { tt_ = s13; s13 = v_; v_ = tt_; }                  \
            if (v_ < s14) { tt_ = s14; s14 = v_; v_ = tt_; }                  \
            s15 = v_;                                                         \
        }                                                                     \
    } while (0)

    for (int j = lane; j < c; j += 64) {
        const int o = order[off + j];
        const float dx = x[3 * o + 0] - xm;
        const float dy = x[3 * o + 1] - ym;
        const float dz = x[3 * o + 2] - zm;
        const float d2 = dx * dx + dy * dy + dz * dz;
        KNN_INSERT(d2);
    }
#undef KNN_INSERT

    // K cooperative pops; after the loop `ans` is the K-th smallest d^2
    // (multiset includes the self-distance 0, matching the reference).
    float ans = FLT_MAX;
    for (int it = 0; it < K; ++it) {
        float v = s0;
        DPP_MIN_STEP(v, 0x111);  // row_shr:1
        DPP_MIN_STEP(v, 0x112);  // row_shr:2
        DPP_MIN_STEP(v, 0x114);  // row_shr:4
        DPP_MIN_STEP(v, 0x118);  // row_shr:8
        DPP_MIN_STEP(v, 0x142);  // row_bcast:15
        DPP_MIN_STEP(v, 0x143);  // row_bcast:31
        const float m = __int_as_float(
            __builtin_amdgcn_readlane(__float_as_int(v), 63));
        ans = m;
        const unsigned long long bal = __ballot(s0 == m);
        const int leader = (int)__ffsll(bal) - 1;
        if (lane == leader) {  // pop exactly one instance (handles ties)
            s0 = s1; s1 = s2; s2 = s3; s3 = s4; s4 = s5; s5 = s6; s6 = s7;
            s7 = s8; s8 = s9; s9 = s10; s10 = s11; s11 = s12; s12 = s13;
            s13 = s14; s14 = s15; s15 = FLT_MAX;
        }
    }

    if (lane == 0) {
        // dim = NI-1 = 2: volume = pi*r^2 = pi*ans (ans is squared distance).
        float p = (c < K) ? (1.0f / (float)c)
                          : (3.14159265358979323846f * ans / (float)(K - 1));
        out[wid] = p;
    }
}

extern "C" void kernel_launch(void* const* d_in, const int* in_sizes, int n_in,
                              void* d_out, int out_size, void* d_ws, size_t ws_size,
                              hipStream_t stream) {
    const float* x   = (const float*)d_in[0];
    const int*   idx = (const int*)d_in[1];
    const int*   Kp  = (const int*)d_in[2];
    float* out = (float*)d_out;

    const int M = in_sizes[1];  // 16384

    int* ws      = (int*)d_ws;
    int* counts  = ws;
    int* offsets = ws + NGROUPS;
    int* order   = ws + 2 * NGROUPS;

    kde_bucket<<<1, 1024, 0, stream>>>(idx, M, counts, offsets, order);

    const int blocks = (M + 3) / 4;  // 4 waves (points) per 256-thread block
    kde_select<<<blocks, 256, 0, stream>>>(x, idx, order, counts, offsets, Kp, M, out);
}